// Round 1
// baseline (2548.013 us; speedup 1.0000x reference)
//
#include <hip/hip_runtime.h>

// LSTM: B=256, T=512, I=64, H=512, G=4H=2048.
// gates = W @ [h; x] with W = [R | kernel^T], concat K = 576.
// Grid decomposition: 256 WGs = 16 batch-groups (16 batch each) x 16 gate-slices
// (32 h-cols each -> 128 W rows, interleaved f,i,c,o per h-col quad so the
// MFMA D-fragment's 4 regs per lane = the 4 gates of one (h_col, batch)).
#define TSTEPS 512
#define BATCH  256
#define ISZ    64
#define HSZ    512
#define GSZ    2048
#define KCAT   576
#define NKT    18   // KCAT / 32
#define MT     8    // 128 rows / 16 per WG
#define BG     16   // batch per group
#define HS     32   // h cols per gate-slice

typedef __attribute__((ext_vector_type(8))) short short8;
typedef __attribute__((ext_vector_type(4))) float f32x4;

static __device__ __forceinline__ unsigned short f2bf(float f) {
    unsigned int u = __float_as_uint(f);
    return (unsigned short)((u + 0x7fffu + ((u >> 16) & 1u)) >> 16);  // RNE
}
static __device__ __forceinline__ float sig_(float x) {
    return 1.0f / (1.0f + __expf(-x));
}
static __device__ __forceinline__ float tanh_(float x) {
    // overflow-safe tanh via exp of negative argument only
    float e = __expf(-2.0f * fabsf(x));
    float t = (1.0f - e) / (1.0f + e);
    return copysignf(t, x);
}

// Pack W = [R | kernel^T] (fp32) into bf16 MFMA A-fragment order.
// Frag index t = ((jj*8 + m)*18 + kt)*64 + lane; each frag = 8 bf16 (16B).
// Local row r = 16m + (lane&15); gate q = r&3; hco = r>>2 (0..31).
// Global gate row = q*512 + jj*32 + hco.  k = kt*32 + (lane>>4)*8 + j.
__global__ void pack_w(const float* __restrict__ R, const float* __restrict__ Kin,
                       unsigned short* __restrict__ wpack)
{
    const int t  = blockIdx.x * 256 + threadIdx.x;   // 576*256 = 147456 frags
    const int l  = t & 63;
    const int kt = (t >> 6) % NKT;
    const int m  = (t / (64 * NKT)) & 7;
    const int jj = t / (64 * NKT * MT);
    const int r   = 16 * m + (l & 15);
    const int q   = r & 3;
    const int hco = r >> 2;
    const int grow  = q * HSZ + jj * HS + hco;
    const int kbase = kt * 32 + (l >> 4) * 8;
    unsigned int pk[4];
#pragma unroll
    for (int p = 0; p < 4; ++p) {
        const int k0 = kbase + 2 * p;
        const int k1 = k0 + 1;
        const float f0 = (k0 < HSZ) ? R[(size_t)grow * HSZ + k0]
                                    : Kin[(size_t)(k0 - HSZ) * GSZ + grow];
        const float f1 = (k1 < HSZ) ? R[(size_t)grow * HSZ + k1]
                                    : Kin[(size_t)(k1 - HSZ) * GSZ + grow];
        pk[p] = (unsigned)f2bf(f0) | ((unsigned)f2bf(f1) << 16);
    }
    uint4 v = make_uint4(pk[0], pk[1], pk[2], pk[3]);
    *reinterpret_cast<uint4*>(wpack + (size_t)t * 8) = v;
}

// One LSTM step. bid = gi*16 + jj (gi = batch group, jj = gate slice).
// hbuf layout: [global_batch][h_col] bf16 (double-buffered by caller).
__global__ __launch_bounds__(256) void lstm_step(
    const unsigned short* __restrict__ wpack,
    const float* __restrict__ input_seq,
    const float* __restrict__ bias,
    const unsigned short* __restrict__ hbuf_r,
    unsigned short* __restrict__ hbuf_w,
    float* __restrict__ cbuf,
    float* __restrict__ hlast,
    int s)
{
    __shared__ unsigned short lds_B[16][584];   // [batch][k], +8 pad (2-way ok)
    __shared__ unsigned short lds_hn[16][40];   // staging of new h (16B-aligned rows)
    const int tid = threadIdx.x;
    const int bid = blockIdx.x;
    const int gi = bid >> 4;
    const int jj = bid & 15;

    // ---- stage B = [h_s ; x_s] tile (576 x 16 bf16) into LDS ----
    {
        const int b  = tid >> 4;
        const int ck = tid & 15;
        if (s > 0) {  // h part; s==0 -> h=0 and the h K-tiles are skipped entirely
            const uint4* src = reinterpret_cast<const uint4*>(
                hbuf_r + ((size_t)(gi * BG + b) * HSZ + ck * 32));
            uint4 a0 = src[0], a1 = src[1], a2 = src[2], a3 = src[3];
            uint4* dst = reinterpret_cast<uint4*>(&lds_B[b][ck * 32]);
            dst[0] = a0; dst[1] = a1; dst[2] = a2; dst[3] = a3;
        }
        // x part: input_seq[b_global][s][0:64] fp32 -> bf16
        const float4 xv = *reinterpret_cast<const float4*>(
            input_seq + (size_t)(gi * BG + b) * (TSTEPS * ISZ) + (size_t)s * ISZ + ck * 4);
        uint2 px;
        px.x = (unsigned)f2bf(xv.x) | ((unsigned)f2bf(xv.y) << 16);
        px.y = (unsigned)f2bf(xv.z) | ((unsigned)f2bf(xv.w) << 16);
        *reinterpret_cast<uint2*>(&lds_B[b][HSZ + ck * 4]) = px;
    }
    __syncthreads();

    // ---- MFMA: D(128x16) = Wslice(128x576) @ B(576x16); wave w owns tiles 2w,2w+1
    const int w  = tid >> 6;
    const int l  = tid & 63;
    const int bb = l & 15;   // batch within group (D col)
    const int lg = l >> 4;
    f32x4 acc0 = {0.f, 0.f, 0.f, 0.f};
    f32x4 acc1 = {0.f, 0.f, 0.f, 0.f};
    const int m0 = 2 * w, m1 = 2 * w + 1;
    const int kt0 = (s == 0) ? 16 : 0;  // step 0: only the x K-tiles
    for (int kt = kt0; kt < NKT; ++kt) {
        const short8 bf = *reinterpret_cast<const short8*>(&lds_B[bb][kt * 32 + lg * 8]);
        const short8 a0 = *reinterpret_cast<const short8*>(
            wpack + (((size_t)(jj * MT + m0) * NKT + kt) * 64 + l) * 8);
        const short8 a1 = *reinterpret_cast<const short8*>(
            wpack + (((size_t)(jj * MT + m1) * NKT + kt) * 64 + l) * 8);
        acc0 = __builtin_amdgcn_mfma_f32_16x16x32_bf16(a0, bf, acc0, 0, 0, 0);
        acc1 = __builtin_amdgcn_mfma_f32_16x16x32_bf16(a1, bf, acc1, 0, 0, 0);
    }

    // ---- lane-local cell update: acc regs 0..3 = f,i,c',o gates of (hco, bb)
#define CELL(ACC, M, T2)                                                        \
    {                                                                           \
        const int hco = 4 * (M) + lg;                                           \
        const int ghc = jj * HS + hco;                                          \
        const float fg = ACC[0] + bias[ghc];                                    \
        const float ig = ACC[1] + bias[HSZ + ghc];                              \
        const float cg = ACC[2] + bias[2 * HSZ + ghc];                          \
        const float og = ACC[3] + bias[3 * HSZ + ghc];                          \
        const size_t cidx = (((size_t)bid * 4 + w) * 2 + (T2)) * 64 + l;        \
        const float c_old = (s == 0) ? 0.f : cbuf[cidx];                        \
        const float c_new = sig_(fg) * c_old + sig_(ig) * tanh_(cg);            \
        cbuf[cidx] = c_new;                                                     \
        const float h = sig_(og) * tanh_(c_new);                                \
        lds_hn[bb][hco] = f2bf(h);                                              \
        if (s == TSTEPS - 1)                                                    \
            hlast[(size_t)(gi * BG + bb) * HSZ + ghc] = h;                      \
    }
    CELL(acc0, m0, 0)
    CELL(acc1, m1, 1)
#undef CELL

    __syncthreads();
    // coalesced h write-out: 16 batches x 32 h-cols bf16 = 1KB
    if (tid < 64) {
        const int b = tid >> 2, c4 = tid & 3;
        uint4 v = *reinterpret_cast<const uint4*>(&lds_hn[b][c4 * 8]);
        *reinterpret_cast<uint4*>(
            hbuf_w + ((size_t)(gi * BG + b) * HSZ + jj * HS + c4 * 8)) = v;
    }
}

// out[b] = h_last[b,:] . Wout + bout
__global__ void out_kernel(const float* __restrict__ hlast,
                           const float* __restrict__ wout,
                           const float* __restrict__ bout,
                           float* __restrict__ out)
{
    const int b = blockIdx.x;
    const int l = threadIdx.x;
    float p = 0.f;
    for (int k = l; k < HSZ; k += 64)
        p += hlast[(size_t)b * HSZ + k] * wout[k];
    for (int off = 32; off > 0; off >>= 1)
        p += __shfl_down(p, off, 64);
    if (l == 0) out[b] = p + bout[0];
}

extern "C" void kernel_launch(void* const* d_in, const int* in_sizes, int n_in,
                              void* d_out, int out_size, void* d_ws, size_t ws_size,
                              hipStream_t stream) {
    const float* input_seq = (const float*)d_in[0];   // (256, 512, 64)
    const float* Kin       = (const float*)d_in[1];   // (64, 2048)
    const float* R         = (const float*)d_in[2];   // (2048, 512)
    const float* bias      = (const float*)d_in[3];   // (2048,)
    const float* Wout      = (const float*)d_in[4];   // (1, 512)
    const float* bout      = (const float*)d_in[5];   // (1,)
    float* out = (float*)d_out;

    char* ws = (char*)d_ws;
    unsigned short* wpack = (unsigned short*)(ws);                       // 2,359,296 B
    float* cbuf           = (float*)(ws + 2359296);                      //   524,288 B
    float* hlast          = (float*)(ws + 2359296 + 524288);             //   524,288 B
    unsigned short* hbuf0 = (unsigned short*)(ws + 2359296 + 1048576);   //   524,288 B x2
    unsigned short* hbuf1 = hbuf0 + (size_t)BATCH * HSZ;

    pack_w<<<dim3(576), dim3(256), 0, stream>>>(R, Kin, wpack);
    for (int s = 0; s < TSTEPS; ++s) {
        const unsigned short* hr = (s & 1) ? hbuf1 : hbuf0;
        unsigned short* hw = ((s + 1) & 1) ? hbuf1 : hbuf0;
        lstm_step<<<dim3(256), dim3(256), 0, stream>>>(
            wpack, input_seq, bias, hr, hw, cbuf, hlast, s);
    }
    out_kernel<<<dim3(256), dim3(64), 0, stream>>>(hlast, Wout, bout, out);
}